// Round 7
// baseline (155.491 us; speedup 1.0000x reference)
//
#include <hip/hip_runtime.h>
#include <hip/hip_fp16.h>
#include <stdint.h>

#define HH 2048
#define WW 2048
#define NS 1024
#define NIMG 64
#define ESZ 256
#define NCOL 69      // x, y, h, w, d, c[64]
#define EPS_T 0.004f // transmittance cutoff; truncation error <= EPS_T

#define NBLK_PREP 4
#define PXPT 4                                        // pixels per thread (interleave)
#define NBLK_IL (NIMG * 65536 / (256 * PXPT))         // 4096 interleave blocks

typedef float    f32x4 __attribute__((ext_vector_type(4)));
typedef uint32_t u32x4 __attribute__((ext_vector_type(4)));

// ---------------------------------------------------------------------------
// Fused kernel. Blocks [0,4): decode+rank 256 samples each. Blocks [4,4+4096):
// planar f32 -> fp16 RGBA interleave, 4 px/thread: each 16B load instruction
// covers whole cache lines (no gaps), so NT loads are single-touch safe.
// ---------------------------------------------------------------------------
__global__ __launch_bounds__(256) void prep_interleave_kernel(const float* __restrict__ data,
                                                              const float* __restrict__ images,
                                                              uint2* __restrict__ hbuf,
                                                              uint32_t* __restrict__ pos) {
    const int tid = threadIdx.x;

    if (blockIdx.x >= NBLK_PREP) {
        // ---- interleave ----
        const size_t g0 = ((size_t)(blockIdx.x - NBLK_PREP) * 256 + tid) * PXPT;
        const size_t img = g0 >> 16;
        const size_t p0  = g0 & 65535;
        const float* base = images + img * (size_t)(4 * 65536) + p0;

        const f32x4 r4 = __builtin_nontemporal_load((const f32x4*)(base));
        const f32x4 g4 = __builtin_nontemporal_load((const f32x4*)(base + 65536));
        const f32x4 b4 = __builtin_nontemporal_load((const f32x4*)(base + 2 * 65536));
        const f32x4 a4 = __builtin_nontemporal_load((const f32x4*)(base + 3 * 65536));

        u32x4 o0, o1;
        __half2 rg0 = __floats2half2_rn(r4.x, g4.x);
        __half2 ba0 = __floats2half2_rn(b4.x, a4.x);
        __half2 rg1 = __floats2half2_rn(r4.y, g4.y);
        __half2 ba1 = __floats2half2_rn(b4.y, a4.y);
        o0.x = *(unsigned int*)&rg0; o0.y = *(unsigned int*)&ba0;
        o0.z = *(unsigned int*)&rg1; o0.w = *(unsigned int*)&ba1;
        __half2 rg2 = __floats2half2_rn(r4.z, g4.z);
        __half2 ba2 = __floats2half2_rn(b4.z, a4.z);
        __half2 rg3 = __floats2half2_rn(r4.w, g4.w);
        __half2 ba3 = __floats2half2_rn(b4.w, a4.w);
        o1.x = *(unsigned int*)&rg2; o1.y = *(unsigned int*)&ba2;
        o1.z = *(unsigned int*)&rg3; o1.w = *(unsigned int*)&ba3;

        u32x4* dst = (u32x4*)(hbuf + g0);
        dst[0] = o0;
        dst[1] = o1;
        return;
    }

    // ---- prep: this block ranks samples [blockIdx*256, +256) ----
    __shared__ float ds[NS];
    #pragma unroll
    for (int k = 0; k < 4; ++k) {
        const int s = tid + 256 * k;
        ds[s] = data[s * NCOL + 4];
    }
    __syncthreads();

    const int s = (int)blockIdx.x * 256 + tid;
    const float* row = data + s * NCOL;
    const float d = ds[s];
    const int x = (int)rintf(row[0] * (float)HH);   // round-half-even == jnp.round
    const int y = (int)rintf(row[1] * (float)WW);
    const int h = (int)rintf(row[2] * (float)HH);
    const int w = (int)rintf(row[3] * (float)WW);
    const int x1 = x - h / 2;
    const int y1 = y - w / 2;

    float best = row[5];
    int bi = 0;
    #pragma unroll 8
    for (int j = 1; j < NIMG; ++j) {
        float v = row[5 + j];
        if (v > best) { best = v; bi = j; }
    }

    int rank = 0;
    for (int j4 = 0; j4 < NS / 4; ++j4) {
        const float4 dj = *(const float4*)&ds[j4 * 4];   // broadcast b128 read
        const int j0 = j4 * 4;
        rank += (int)((dj.x < d) | ((dj.x == d) & (j0     < s)));
        rank += (int)((dj.y < d) | ((dj.y == d) & (j0 + 1 < s)));
        rank += (int)((dj.z < d) | ((dj.z == d) & (j0 + 2 < s)));
        rank += (int)((dj.w < d) | ((dj.w == d) & (j0 + 3 < s)));
    }
    pos[rank] = ((uint32_t)x1 << 17) | ((uint32_t)y1 << 6) | (uint32_t)bi;
}

// ---------------------------------------------------------------------------
// Composite: one block per 32x64 tile, 8 px/thread (2x4 quadrants of 16x16)
// for 8 independent load streams per list entry. Front-to-back transmittance,
// per-lane predicated loads, wave-level early termination, NT output stores.
// ---------------------------------------------------------------------------
__global__ __launch_bounds__(256) void comp_half_kernel(const uint2* __restrict__ hbuf,
                                                        const uint32_t* __restrict__ pos,
                                                        float* __restrict__ out) {
    __shared__ uint32_t list[NS];
    __shared__ int wcnt[4];

    const int tid  = threadIdx.x;
    const int lane = tid & 63;
    const int wv   = tid >> 6;

    const int tileR = blockIdx.x >> 5;    // 64 (rows of 32) x 32 (cols of 64) grid
    const int tileC = blockIdx.x & 31;
    const int r0 = tileR * 32;
    const int c0 = tileC * 64;

    // ---- binning: sprites whose bbox intersects this 32x64 tile ----
    int run = 0;
    for (int base = 0; base < NS; base += 256) {
        const uint32_t p = pos[base + tid];
        const int x1 = (int)(p >> 17);
        const int y1 = (int)((p >> 6) & 0x7FF);
        const bool hit = (x1 >= r0 - (ESZ - 1)) && (x1 <= r0 + 31) &&
                         (y1 >= c0 - (ESZ - 1)) && (y1 <= c0 + 63);
        const uint64_t m = __ballot(hit);
        if (lane == 0) wcnt[wv] = __popcll(m);
        __syncthreads();
        int off = run;
        for (int w2 = 0; w2 < wv; ++w2) off += wcnt[w2];
        if (hit) {
            const int slot = __popcll(m & ((1ull << lane) - 1ull));
            list[off + slot] = p;
        }
        run += wcnt[0] + wcnt[1] + wcnt[2] + wcnt[3];
        __syncthreads();
    }
    const int n = run;

    // ---- per-thread: 8 pixels (2 row-quadrants x 4 col-quadrants of 16x16) ----
    const int px0 = c0 + (tid & 15);
    const int py0 = r0 + (tid >> 4);

    float cr[8], cg[8], cb[8], T[8];
    #pragma unroll
    for (int q = 0; q < 8; ++q) { cr[q] = 0.0f; cg[q] = 0.0f; cb[q] = 0.0f; T[q] = 1.0f; }

    // front-to-back: list is sorted back-to-front, so walk it in reverse
    for (int s = n - 1; s >= 0; --s) {
        const uint32_t p = list[s];                 // uniform -> LDS broadcast
        const int x1 = (int)(p >> 17);
        const int y1 = (int)((p >> 6) & 0x7FF);
        const size_t ib = ((size_t)(p & 0x3F)) << 16;
        const int ry = py0 - x1;
        const int rx = px0 - y1;
        #pragma unroll
        for (int q = 0; q < 8; ++q) {
            if (T[q] > EPS_T) {
                const int sy = ry + ((q >> 2) << 4);
                const int sx = rx + ((q & 3) << 4);
                if ((unsigned)sy < ESZ && (unsigned)sx < ESZ) {
                    const uint2 v = hbuf[ib + (size_t)((sy << 8) + sx)];
                    const __half2 rg = *(const __half2*)&v.x;
                    const __half2 ba = *(const __half2*)&v.y;
                    const float sr = __low2float(rg);
                    const float sg = __high2float(rg);
                    const float sb = __low2float(ba);
                    const float a  = __high2float(ba);
                    const float w  = T[q] * a;
                    cr[q] += w * sr;
                    cg[q] += w * sg;
                    cb[q] += w * sb;
                    T[q] *= (1.0f - a);
                }
            }
        }
        bool alive = false;
        #pragma unroll
        for (int q = 0; q < 8; ++q) alive |= (T[q] > EPS_T);
        if (!__any(alive)) break;
    }

    #pragma unroll
    for (int q = 0; q < 8; ++q) {
        const int py = py0 + ((q >> 2) << 4);
        const int px = px0 + ((q & 3) << 4);
        const size_t o = (size_t)py * WW + px;
        __builtin_nontemporal_store(cr[q] + T[q], out + o);
        __builtin_nontemporal_store(cg[q] + T[q], out + (size_t)HH * WW + o);
        __builtin_nontemporal_store(cb[q] + T[q], out + (size_t)2 * HH * WW + o);
        __builtin_nontemporal_store(1.0f,         out + (size_t)3 * HH * WW + o);
    }
}

// ---------------------------------------------------------------------------
// Fallback (fp32 planar, back-to-front "over") — only if ws too small.
// ---------------------------------------------------------------------------
__global__ __launch_bounds__(1024) void prep_kernel(const float* __restrict__ data,
                                                    uint32_t* __restrict__ pos) {
    __shared__ float ds[NS];
    const int t = threadIdx.x;
    const float* row = data + t * NCOL;
    const float d = row[4];
    const int x = (int)rintf(row[0] * (float)HH);
    const int y = (int)rintf(row[1] * (float)WW);
    const int h = (int)rintf(row[2] * (float)HH);
    const int w = (int)rintf(row[3] * (float)WW);
    const int x1 = x - h / 2;
    const int y1 = y - w / 2;
    float best = row[5];
    int bi = 0;
    for (int j = 1; j < NIMG; ++j) {
        float v = row[5 + j];
        if (v > best) { best = v; bi = j; }
    }
    ds[t] = d;
    __syncthreads();
    int rank = 0;
    for (int j = 0; j < NS; ++j) {
        float dj = ds[j];
        rank += (int)((dj < d) | ((dj == d) & (j < t)));
    }
    pos[rank] = ((uint32_t)x1 << 17) | ((uint32_t)y1 << 6) | (uint32_t)bi;
}

__global__ __launch_bounds__(256) void comp_kernel(const float* __restrict__ images,
                                                   const uint32_t* __restrict__ pos,
                                                   float* __restrict__ out) {
    __shared__ uint32_t list[NS];
    __shared__ int wcnt[4];
    const int tid  = threadIdx.x;
    const int lane = tid & 63;
    const int wv   = tid >> 6;
    const int tileR = blockIdx.x >> 7;
    const int tileC = blockIdx.x & 127;
    const int r0 = tileR * 16;
    const int c0 = tileC * 16;
    int run = 0;
    for (int base = 0; base < NS; base += 256) {
        const uint32_t p = pos[base + tid];
        const int x1 = (int)(p >> 17);
        const int y1 = (int)((p >> 6) & 0x7FF);
        const bool hit = (x1 >= r0 - (ESZ - 1)) && (x1 <= r0 + 15) &&
                         (y1 >= c0 - (ESZ - 1)) && (y1 <= c0 + 15);
        const uint64_t m = __ballot(hit);
        if (lane == 0) wcnt[wv] = __popcll(m);
        __syncthreads();
        int off = run;
        for (int w2 = 0; w2 < wv; ++w2) off += wcnt[w2];
        if (hit) {
            const int slot = __popcll(m & ((1ull << lane) - 1ull));
            list[off + slot] = p;
        }
        run += wcnt[0] + wcnt[1] + wcnt[2] + wcnt[3];
        __syncthreads();
    }
    const int n = run;
    const int px = c0 + (tid & 15);
    const int py = r0 + (tid >> 4);
    float r = 1.0f, g = 1.0f, b = 1.0f;
    for (int s = 0; s < n; ++s) {
        const uint32_t p = list[s];
        const int x1 = (int)(p >> 17);
        const int y1 = (int)((p >> 6) & 0x7FF);
        const int ii = (int)(p & 0x3F);
        const int sy = py - x1;
        const int sx = px - y1;
        if ((unsigned)sy < ESZ && (unsigned)sx < ESZ) {
            const float* sp = images + (size_t)ii * (4 * ESZ * ESZ) + sy * ESZ + sx;
            const float sr = sp[0];
            const float sg = sp[ESZ * ESZ];
            const float sb = sp[2 * ESZ * ESZ];
            const float a  = sp[3 * ESZ * ESZ];
            const float ia = 1.0f - a;
            r = r * ia + sr * a;
            g = g * ia + sg * a;
            b = b * ia + sb * a;
        }
    }
    const size_t o = (size_t)py * WW + px;
    out[o]                        = r;
    out[(size_t)HH * WW     + o]  = g;
    out[(size_t)2 * HH * WW + o]  = b;
    out[(size_t)3 * HH * WW + o]  = 1.0f;
}

extern "C" void kernel_launch(void* const* d_in, const int* in_sizes, int n_in,
                              void* d_out, int out_size, void* d_ws, size_t ws_size,
                              hipStream_t stream) {
    const float* data   = (const float*)d_in[0];
    const float* images = (const float*)d_in[1];
    float* out          = (float*)d_out;

    uint32_t* pos = (uint32_t*)d_ws;                           // 4 KB
    const size_t hbuf_off = 4096;
    const size_t hbuf_bytes = (size_t)NIMG * 65536 * 8;        // 33.5 MB fp16 RGBA

    if (ws_size >= hbuf_off + hbuf_bytes) {
        uint2* hbuf = (uint2*)((char*)d_ws + hbuf_off);
        prep_interleave_kernel<<<NBLK_PREP + NBLK_IL, 256, 0, stream>>>(data, images, hbuf, pos);
        comp_half_kernel<<<(HH / 32) * (WW / 64), 256, 0, stream>>>(hbuf, pos, out);
    } else {
        prep_kernel<<<1, NS, 0, stream>>>(data, pos);
        comp_kernel<<<(HH / 16) * (WW / 16), 256, 0, stream>>>(images, pos, out);
    }
}

// Round 8
// 121.837 us; speedup vs baseline: 1.2762x; 1.2762x over previous
//
#include <hip/hip_runtime.h>
#include <hip/hip_fp16.h>
#include <stdint.h>

#define HH 2048
#define WW 2048
#define NS 1024
#define NIMG 64
#define ESZ 256
#define NCOL 69      // x, y, h, w, d, c[64]
#define EPS_T 0.006f // transmittance cutoff; truncation error <= EPS_T

#define NBLK_PREP 4
#define PXPT 4                                        // pixels per thread (interleave)
#define NBLK_IL (NIMG * 65536 / (256 * PXPT))         // 4096 interleave blocks

typedef float    f32x4 __attribute__((ext_vector_type(4)));
typedef uint32_t u32x4 __attribute__((ext_vector_type(4)));

// ---------------------------------------------------------------------------
// Fused kernel. Blocks [0,4): decode+rank 256 samples each. Blocks [4,4+4096):
// planar f32 -> fp16 RGBA interleave, 4 px/thread, plain vector loads/stores
// (measured: NT hints hurt this stream — R4 pattern is fastest).
// ---------------------------------------------------------------------------
__global__ __launch_bounds__(256) void prep_interleave_kernel(const float* __restrict__ data,
                                                              const float* __restrict__ images,
                                                              uint2* __restrict__ hbuf,
                                                              uint32_t* __restrict__ pos) {
    const int tid = threadIdx.x;

    if (blockIdx.x >= NBLK_PREP) {
        // ---- interleave ----
        const size_t g0 = ((size_t)(blockIdx.x - NBLK_PREP) * 256 + tid) * PXPT;
        const size_t img = g0 >> 16;
        const size_t p0  = g0 & 65535;
        const float* base = images + img * (size_t)(4 * 65536) + p0;

        const f32x4 r4 = *(const f32x4*)(base);
        const f32x4 g4 = *(const f32x4*)(base + 65536);
        const f32x4 b4 = *(const f32x4*)(base + 2 * 65536);
        const f32x4 a4 = *(const f32x4*)(base + 3 * 65536);

        u32x4 o0, o1;
        __half2 rg0 = __floats2half2_rn(r4.x, g4.x);
        __half2 ba0 = __floats2half2_rn(b4.x, a4.x);
        __half2 rg1 = __floats2half2_rn(r4.y, g4.y);
        __half2 ba1 = __floats2half2_rn(b4.y, a4.y);
        o0.x = *(unsigned int*)&rg0; o0.y = *(unsigned int*)&ba0;
        o0.z = *(unsigned int*)&rg1; o0.w = *(unsigned int*)&ba1;
        __half2 rg2 = __floats2half2_rn(r4.z, g4.z);
        __half2 ba2 = __floats2half2_rn(b4.z, a4.z);
        __half2 rg3 = __floats2half2_rn(r4.w, g4.w);
        __half2 ba3 = __floats2half2_rn(b4.w, a4.w);
        o1.x = *(unsigned int*)&rg2; o1.y = *(unsigned int*)&ba2;
        o1.z = *(unsigned int*)&rg3; o1.w = *(unsigned int*)&ba3;

        u32x4* dst = (u32x4*)(hbuf + g0);
        dst[0] = o0;
        dst[1] = o1;
        return;
    }

    // ---- prep: this block ranks samples [blockIdx*256, +256) ----
    __shared__ float ds[NS];
    #pragma unroll
    for (int k = 0; k < 4; ++k) {
        const int s = tid + 256 * k;
        ds[s] = data[s * NCOL + 4];
    }
    __syncthreads();

    const int s = (int)blockIdx.x * 256 + tid;
    const float* row = data + s * NCOL;
    const float d = ds[s];
    const int x = (int)rintf(row[0] * (float)HH);   // round-half-even == jnp.round
    const int y = (int)rintf(row[1] * (float)WW);
    const int h = (int)rintf(row[2] * (float)HH);
    const int w = (int)rintf(row[3] * (float)WW);
    const int x1 = x - h / 2;
    const int y1 = y - w / 2;

    float best = row[5];
    int bi = 0;
    #pragma unroll 8
    for (int j = 1; j < NIMG; ++j) {
        float v = row[5 + j];
        if (v > best) { best = v; bi = j; }
    }

    int rank = 0;
    for (int j4 = 0; j4 < NS / 4; ++j4) {
        const float4 dj = *(const float4*)&ds[j4 * 4];   // broadcast b128 read
        const int j0 = j4 * 4;
        rank += (int)((dj.x < d) | ((dj.x == d) & (j0     < s)));
        rank += (int)((dj.y < d) | ((dj.y == d) & (j0 + 1 < s)));
        rank += (int)((dj.z < d) | ((dj.z == d) & (j0 + 2 < s)));
        rank += (int)((dj.w < d) | ((dj.w == d) & (j0 + 3 < s)));
    }
    pos[rank] = ((uint32_t)x1 << 17) | ((uint32_t)y1 << 6) | (uint32_t)bi;
}

// ---------------------------------------------------------------------------
// Composite: one block per 32x32 tile, 4 px/thread (measured-best config).
// Front-to-back transmittance, per-lane predicated loads, wave-level early
// termination, NT output stores.
// ---------------------------------------------------------------------------
__global__ __launch_bounds__(256) void comp_half_kernel(const uint2* __restrict__ hbuf,
                                                        const uint32_t* __restrict__ pos,
                                                        float* __restrict__ out) {
    __shared__ uint32_t list[NS];
    __shared__ int wcnt[4];

    const int tid  = threadIdx.x;
    const int lane = tid & 63;
    const int wv   = tid >> 6;

    const int tileR = blockIdx.x >> 6;    // 64x64 tiles of 32x32
    const int tileC = blockIdx.x & 63;
    const int r0 = tileR * 32;
    const int c0 = tileC * 32;

    // ---- binning: sprites whose bbox intersects this tile (depth order) ----
    int run = 0;
    for (int base = 0; base < NS; base += 256) {
        const uint32_t p = pos[base + tid];
        const int x1 = (int)(p >> 17);
        const int y1 = (int)((p >> 6) & 0x7FF);
        const bool hit = (x1 >= r0 - (ESZ - 1)) && (x1 <= r0 + 31) &&
                         (y1 >= c0 - (ESZ - 1)) && (y1 <= c0 + 31);
        const uint64_t m = __ballot(hit);
        if (lane == 0) wcnt[wv] = __popcll(m);
        __syncthreads();
        int off = run;
        for (int w2 = 0; w2 < wv; ++w2) off += wcnt[w2];
        if (hit) {
            const int slot = __popcll(m & ((1ull << lane) - 1ull));
            list[off + slot] = p;
        }
        run += wcnt[0] + wcnt[1] + wcnt[2] + wcnt[3];
        __syncthreads();
    }
    const int n = run;

    // ---- per-thread: 4 pixels (16x16 quadrants of the 32x32 tile) ----
    const int px0 = c0 + (tid & 15);
    const int py0 = r0 + (tid >> 4);

    float cr[4], cg[4], cb[4], T[4];
    #pragma unroll
    for (int q = 0; q < 4; ++q) { cr[q] = 0.0f; cg[q] = 0.0f; cb[q] = 0.0f; T[q] = 1.0f; }

    // front-to-back: list is sorted back-to-front, so walk it in reverse
    for (int s = n - 1; s >= 0; --s) {
        const uint32_t p = list[s];                 // uniform -> LDS broadcast
        const int x1 = (int)(p >> 17);
        const int y1 = (int)((p >> 6) & 0x7FF);
        const size_t ib = ((size_t)(p & 0x3F)) << 16;
        const int ry = py0 - x1;
        const int rx = px0 - y1;
        #pragma unroll
        for (int q = 0; q < 4; ++q) {
            if (T[q] > EPS_T) {
                const int sy = ry + ((q >> 1) << 4);
                const int sx = rx + ((q & 1) << 4);
                if ((unsigned)sy < ESZ && (unsigned)sx < ESZ) {
                    const uint2 v = hbuf[ib + (size_t)((sy << 8) + sx)];
                    const __half2 rg = *(const __half2*)&v.x;
                    const __half2 ba = *(const __half2*)&v.y;
                    const float sr = __low2float(rg);
                    const float sg = __high2float(rg);
                    const float sb = __low2float(ba);
                    const float a  = __high2float(ba);
                    const float w  = T[q] * a;
                    cr[q] += w * sr;
                    cg[q] += w * sg;
                    cb[q] += w * sb;
                    T[q] *= (1.0f - a);
                }
            }
        }
        const bool alive = (T[0] > EPS_T) | (T[1] > EPS_T) | (T[2] > EPS_T) | (T[3] > EPS_T);
        if (!__any(alive)) break;
    }

    #pragma unroll
    for (int q = 0; q < 4; ++q) {
        const int py = py0 + ((q >> 1) << 4);
        const int px = px0 + ((q & 1) << 4);
        const size_t o = (size_t)py * WW + px;
        __builtin_nontemporal_store(cr[q] + T[q], out + o);
        __builtin_nontemporal_store(cg[q] + T[q], out + (size_t)HH * WW + o);
        __builtin_nontemporal_store(cb[q] + T[q], out + (size_t)2 * HH * WW + o);
        __builtin_nontemporal_store(1.0f,         out + (size_t)3 * HH * WW + o);
    }
}

// ---------------------------------------------------------------------------
// Fallback (fp32 planar, back-to-front "over") — only if ws too small.
// ---------------------------------------------------------------------------
__global__ __launch_bounds__(1024) void prep_kernel(const float* __restrict__ data,
                                                    uint32_t* __restrict__ pos) {
    __shared__ float ds[NS];
    const int t = threadIdx.x;
    const float* row = data + t * NCOL;
    const float d = row[4];
    const int x = (int)rintf(row[0] * (float)HH);
    const int y = (int)rintf(row[1] * (float)WW);
    const int h = (int)rintf(row[2] * (float)HH);
    const int w = (int)rintf(row[3] * (float)WW);
    const int x1 = x - h / 2;
    const int y1 = y - w / 2;
    float best = row[5];
    int bi = 0;
    for (int j = 1; j < NIMG; ++j) {
        float v = row[5 + j];
        if (v > best) { best = v; bi = j; }
    }
    ds[t] = d;
    __syncthreads();
    int rank = 0;
    for (int j = 0; j < NS; ++j) {
        float dj = ds[j];
        rank += (int)((dj < d) | ((dj == d) & (j < t)));
    }
    pos[rank] = ((uint32_t)x1 << 17) | ((uint32_t)y1 << 6) | (uint32_t)bi;
}

__global__ __launch_bounds__(256) void comp_kernel(const float* __restrict__ images,
                                                   const uint32_t* __restrict__ pos,
                                                   float* __restrict__ out) {
    __shared__ uint32_t list[NS];
    __shared__ int wcnt[4];
    const int tid  = threadIdx.x;
    const int lane = tid & 63;
    const int wv   = tid >> 6;
    const int tileR = blockIdx.x >> 7;
    const int tileC = blockIdx.x & 127;
    const int r0 = tileR * 16;
    const int c0 = tileC * 16;
    int run = 0;
    for (int base = 0; base < NS; base += 256) {
        const uint32_t p = pos[base + tid];
        const int x1 = (int)(p >> 17);
        const int y1 = (int)((p >> 6) & 0x7FF);
        const bool hit = (x1 >= r0 - (ESZ - 1)) && (x1 <= r0 + 15) &&
                         (y1 >= c0 - (ESZ - 1)) && (y1 <= c0 + 15);
        const uint64_t m = __ballot(hit);
        if (lane == 0) wcnt[wv] = __popcll(m);
        __syncthreads();
        int off = run;
        for (int w2 = 0; w2 < wv; ++w2) off += wcnt[w2];
        if (hit) {
            const int slot = __popcll(m & ((1ull << lane) - 1ull));
            list[off + slot] = p;
        }
        run += wcnt[0] + wcnt[1] + wcnt[2] + wcnt[3];
        __syncthreads();
    }
    const int n = run;
    const int px = c0 + (tid & 15);
    const int py = r0 + (tid >> 4);
    float r = 1.0f, g = 1.0f, b = 1.0f;
    for (int s = 0; s < n; ++s) {
        const uint32_t p = list[s];
        const int x1 = (int)(p >> 17);
        const int y1 = (int)((p >> 6) & 0x7FF);
        const int ii = (int)(p & 0x3F);
        const int sy = py - x1;
        const int sx = px - y1;
        if ((unsigned)sy < ESZ && (unsigned)sx < ESZ) {
            const float* sp = images + (size_t)ii * (4 * ESZ * ESZ) + sy * ESZ + sx;
            const float sr = sp[0];
            const float sg = sp[ESZ * ESZ];
            const float sb = sp[2 * ESZ * ESZ];
            const float a  = sp[3 * ESZ * ESZ];
            const float ia = 1.0f - a;
            r = r * ia + sr * a;
            g = g * ia + sg * a;
            b = b * ia + sb * a;
        }
    }
    const size_t o = (size_t)py * WW + px;
    out[o]                        = r;
    out[(size_t)HH * WW     + o]  = g;
    out[(size_t)2 * HH * WW + o]  = b;
    out[(size_t)3 * HH * WW + o]  = 1.0f;
}

extern "C" void kernel_launch(void* const* d_in, const int* in_sizes, int n_in,
                              void* d_out, int out_size, void* d_ws, size_t ws_size,
                              hipStream_t stream) {
    const float* data   = (const float*)d_in[0];
    const float* images = (const float*)d_in[1];
    float* out          = (float*)d_out;

    uint32_t* pos = (uint32_t*)d_ws;                           // 4 KB
    const size_t hbuf_off = 4096;
    const size_t hbuf_bytes = (size_t)NIMG * 65536 * 8;        // 33.5 MB fp16 RGBA

    if (ws_size >= hbuf_off + hbuf_bytes) {
        uint2* hbuf = (uint2*)((char*)d_ws + hbuf_off);
        prep_interleave_kernel<<<NBLK_PREP + NBLK_IL, 256, 0, stream>>>(data, images, hbuf, pos);
        comp_half_kernel<<<(HH / 32) * (WW / 32), 256, 0, stream>>>(hbuf, pos, out);
    } else {
        prep_kernel<<<1, NS, 0, stream>>>(data, pos);
        comp_kernel<<<(HH / 16) * (WW / 16), 256, 0, stream>>>(images, pos, out);
    }
}